// Round 1
// baseline (943.902 us; speedup 1.0000x reference)
//
#include <hip/hip_runtime.h>

typedef __bf16  bf16x8 __attribute__((ext_vector_type(8)));
typedef float   f32x4  __attribute__((ext_vector_type(4)));

#define MFMA16(a,b,c) __builtin_amdgcn_mfma_f32_16x16x32_bf16((a),(b),(c),0,0,0)

// bf16 weight arena layout in d_ws (elements)
enum : int {
    OFF_W0 = 0,                      // [256][64]
    OFF_W1 = OFF_W0 + 256 * 64,      // [256][256]
    OFF_W2 = OFF_W1 + 256 * 256,
    OFF_W3 = OFF_W2 + 256 * 256,
    OFF_W4 = OFF_W3 + 256 * 256,     // [256][320]
    OFF_W5 = OFF_W4 + 256 * 320,
    OFF_W6 = OFF_W5 + 256 * 256,
    OFF_W7 = OFF_W6 + 256 * 256,
    OFF_WF = OFF_W7 + 256 * 256,     // [256][256]
    OFF_WD = OFF_WF + 256 * 256,     // [128][288]
    W_TOTAL = OFF_WD + 128 * 288     // 593920 elements = 1.19 MB bf16
};

__device__ __forceinline__ unsigned short f2bf(float f) {
    unsigned int u = __float_as_uint(f);
    u += 0x7FFFu + ((u >> 16) & 1u);   // round-to-nearest-even
    return (unsigned short)(u >> 16);
}

// Write Wt[n][k] (bf16, k padded) from src[fin][fout] f32.
// k < n1            -> src row k
// n1 <= k < n2      -> 0 (pad)
// n2 <= k < n3      -> src row k-(n2-n1)   (post-gap rows, layer-4 concat)
// k >= n3           -> 0
__device__ __forceinline__ void prep_one(const float* __restrict__ src,
                                         unsigned short* __restrict__ dst,
                                         int fout, int Kp, int n1, int n2, int n3,
                                         int idx) {
    int n = idx / Kp;
    int k = idx - n * Kp;
    float v = 0.f;
    if (k < n1)                 v = src[k * fout + n];
    else if (k >= n2 && k < n3) v = src[(k - (n2 - n1)) * fout + n];
    dst[n * Kp + k] = f2bf(v);
}

__global__ void prep_kernel(const float* w0, const float* w1, const float* w2,
                            const float* w3, const float* w4, const float* w5,
                            const float* w6, const float* w7, const float* wf,
                            const float* wd, unsigned short* dst) {
    int i = blockIdx.x * 256 + threadIdx.x;
    if (i < 256 * 64)  { prep_one(w0, dst + OFF_W0, 256,  64,  63,  64,  64, i); return; }
    i -= 256 * 64;
    if (i < 256 * 256) { prep_one(w1, dst + OFF_W1, 256, 256, 256, 256, 256, i); return; }
    i -= 256 * 256;
    if (i < 256 * 256) { prep_one(w2, dst + OFF_W2, 256, 256, 256, 256, 256, i); return; }
    i -= 256 * 256;
    if (i < 256 * 256) { prep_one(w3, dst + OFF_W3, 256, 256, 256, 256, 256, i); return; }
    i -= 256 * 256;
    if (i < 256 * 320) { prep_one(w4, dst + OFF_W4, 256, 320,  63,  64, 320, i); return; }
    i -= 256 * 320;
    if (i < 256 * 256) { prep_one(w5, dst + OFF_W5, 256, 256, 256, 256, 256, i); return; }
    i -= 256 * 256;
    if (i < 256 * 256) { prep_one(w6, dst + OFF_W6, 256, 256, 256, 256, 256, i); return; }
    i -= 256 * 256;
    if (i < 256 * 256) { prep_one(w7, dst + OFF_W7, 256, 256, 256, 256, 256, i); return; }
    i -= 256 * 256;
    if (i < 256 * 256) { prep_one(wf, dst + OFF_WF, 256, 256, 256, 256, 256, i); return; }
    i -= 256 * 256;
    if (i < 128 * 288) { prep_one(wd, dst + OFF_WD, 128, 288, 286, 288, 288, i); return; }
}

struct Params {
    const float* x;
    const unsigned short* Wt;
    const float* b[8];
    const float* bfv;   // bf
    const float* bdv;   // bd
    const float* wsv;   // ws (256)
    const float* bsv;   // bs (1)
    const float* wrv;   // wr (128x3)
    const float* brv;   // br (3)
    float* out;
};

// 64 rows/block, 4 waves. LDS swizzle: byte ^= (row&7)<<4 (spreads stride-512B
// ds_read_b128 across banks; 2-way residual conflict = free per G4/m136).
__global__ __launch_bounds__(256) void nerf_kernel(Params P) {
    __shared__ char HsB[64 * 512];   // activations, 64 x 256 bf16
    __shared__ char XsB[64 * 128];   // xyz input padded to 64 cols bf16
    __shared__ char DsB[64 * 64];    // dir features padded to 32 cols bf16

    const int t    = threadIdx.x;
    const int lane = t & 63;
    const int wave = t >> 6;
    const int lr   = lane & 15;               // A-row / B-col / C-col within tile
    const int lk8  = (lane >> 4) << 3;        // k offset (elements)
    const int lkb  = lk8 << 1;                // k offset (bytes)
    const int crow = (lane >> 4) << 2;        // C/D row base within tile
    const int blockRow = blockIdx.x << 6;

    // ---------------- stage input tile ----------------
    {
        const float4* xb = (const float4*)(P.x + (size_t)blockRow * 93);
        for (int i = t; i < 1488; i += 256) {            // 64*93/4 float4s
            float4 v = xb[i];
            float vv[4] = {v.x, v.y, v.z, v.w};
#pragma unroll
            for (int j = 0; j < 4; ++j) {
                int e = (i << 2) + j;
                int r = e / 93;
                int c = e - r * 93;
                unsigned short us = f2bf(vv[j]);
                if (c < 63) {
                    *(unsigned short*)(XsB + ((r * 128 + c * 2) ^ ((r & 7) << 4))) = us;
                } else {
                    int cd = c - 63;
                    *(unsigned short*)(DsB + ((r * 64 + cd * 2) ^ ((r & 7) << 4))) = us;
                }
            }
        }
        if (t < 64) {  // zero pads: Xs col63, Ds cols 30,31
            int r = t;
            *(unsigned short*)(XsB + ((r * 128 + 126) ^ ((r & 7) << 4))) = 0;
            *(unsigned short*)(DsB + ((r * 64 + 60) ^ ((r & 7) << 4))) = 0;
            *(unsigned short*)(DsB + ((r * 64 + 62) ^ ((r & 7) << 4))) = 0;
        }
    }
    __syncthreads();

    // A-fragment getters (row = l&15 of tile, k = (l>>4)*8 + i, contiguous 16B)
    auto ldsA_hs = [&](int mt, int ktL) -> bf16x8 {
        int row = (mt << 4) + lr;
        int off = (row * 512 + (ktL << 6) + lkb) ^ ((row & 7) << 4);
        return *(const bf16x8*)(HsB + off);
    };
    auto ldsA_xs = [&](int mt, int ktL) -> bf16x8 {
        int row = (mt << 4) + lr;
        int off = (row * 128 + (ktL << 6) + lkb) ^ ((row & 7) << 4);
        return *(const bf16x8*)(XsB + off);
    };
    auto ldsA_ds = [&](int mt) -> bf16x8 {
        int row = (mt << 4) + lr;
        int off = (row * 64 + lkb) ^ ((row & 7) << 4);
        return *(const bf16x8*)(DsB + off);
    };
    // B fragment: Wt[n][k], col = l&15, k = (l>>4)*8+i contiguous
    auto ldB = [&](const unsigned short* W, int Kp, int n, int kt) -> bf16x8 {
        return *(const bf16x8*)(W + (size_t)n * Kp + (kt << 5) + lk8);
    };

    // generic 256-wide-output layer: acc 4x4, write relu'd bf16 back to Hs
    auto gemmN4 = [&](auto&& getA, int KT, const unsigned short* W, int Kp,
                      const float* bias, bool dorelu) {
        f32x4 acc[4][4];
#pragma unroll
        for (int mt = 0; mt < 4; ++mt)
#pragma unroll
            for (int nt = 0; nt < 4; ++nt) { f32x4 z = {0.f,0.f,0.f,0.f}; acc[mt][nt] = z; }
        for (int kt = 0; kt < KT; ++kt) {
            bf16x8 a0 = getA(0, kt), a1 = getA(1, kt), a2 = getA(2, kt), a3 = getA(3, kt);
#pragma unroll
            for (int nt = 0; nt < 4; ++nt) {
                bf16x8 b = ldB(W, Kp, (wave << 6) + (nt << 4) + lr, kt);
                acc[0][nt] = MFMA16(a0, b, acc[0][nt]);
                acc[1][nt] = MFMA16(a1, b, acc[1][nt]);
                acc[2][nt] = MFMA16(a2, b, acc[2][nt]);
                acc[3][nt] = MFMA16(a3, b, acc[3][nt]);
            }
        }
        __syncthreads();   // all waves done reading Hs before in-place write
#pragma unroll
        for (int nt = 0; nt < 4; ++nt) {
            int col = (wave << 6) + (nt << 4) + lr;
            float bv = bias[col];
#pragma unroll
            for (int mt = 0; mt < 4; ++mt) {
#pragma unroll
                for (int e = 0; e < 4; ++e) {
                    int row = (mt << 4) + crow + e;
                    float z = acc[mt][nt][e] + bv;
                    if (dorelu) z = fmaxf(z, 0.f);
                    *(unsigned short*)(HsB + ((row * 512 + col * 2) ^ ((row & 7) << 4))) = f2bf(z);
                }
            }
        }
        __syncthreads();
    };

    const unsigned short* Wt = P.Wt;

    // layer 0: K=64 from Xs
    gemmN4([&](int mt, int kt) { return ldsA_xs(mt, kt); }, 2, Wt + OFF_W0, 64, P.b[0], true);
    // layers 1-3
    gemmN4([&](int mt, int kt) { return ldsA_hs(mt, kt); }, 8, Wt + OFF_W1, 256, P.b[1], true);
    gemmN4([&](int mt, int kt) { return ldsA_hs(mt, kt); }, 8, Wt + OFF_W2, 256, P.b[2], true);
    gemmN4([&](int mt, int kt) { return ldsA_hs(mt, kt); }, 8, Wt + OFF_W3, 256, P.b[3], true);
    // layer 4: concat([xyz, h]) -> k 0..63 from Xs, 64..319 from Hs
    gemmN4([&](int mt, int kt) { return kt < 2 ? ldsA_xs(mt, kt) : ldsA_hs(mt, kt - 2); },
           10, Wt + OFF_W4, 320, P.b[4], true);
    // layers 5-7
    gemmN4([&](int mt, int kt) { return ldsA_hs(mt, kt); }, 8, Wt + OFF_W5, 256, P.b[5], true);
    gemmN4([&](int mt, int kt) { return ldsA_hs(mt, kt); }, 8, Wt + OFF_W6, 256, P.b[6], true);
    gemmN4([&](int mt, int kt) { return ldsA_hs(mt, kt); }, 8, Wt + OFF_W7, 256, P.b[7], true);

    // sigma = h @ ws + bs  (VALU, 4 threads/row, reads Hs=h before wf overwrites)
    {
        int rr = t >> 2, q = t & 3;
        float sig = 0.f;
#pragma unroll
        for (int j = 0; j < 8; ++j) {
            int cb = q * 64 + j * 8;
            bf16x8 h8 = *(const bf16x8*)(HsB + ((rr * 512 + cb * 2) ^ ((rr & 7) << 4)));
#pragma unroll
            for (int e = 0; e < 8; ++e) sig += (float)h8[e] * P.wsv[cb + e];
        }
        sig += __shfl_xor(sig, 1);
        sig += __shfl_xor(sig, 2);
        if (q == 0) P.out[(size_t)(blockRow + rr) * 4 + 3] = sig + P.bsv[0];
    }

    // xyz_final = h @ wf + bf (NO relu) -> Hs
    gemmN4([&](int mt, int kt) { return ldsA_hs(mt, kt); }, 8, Wt + OFF_WF, 256, P.bfv, false);

    // d = relu(concat([xyz_final, dir]) @ wd + bd): K=288, N=128 -> Hs cols 0..127
    {
        f32x4 acc[4][2];
#pragma unroll
        for (int mt = 0; mt < 4; ++mt)
#pragma unroll
            for (int nt = 0; nt < 2; ++nt) { f32x4 z = {0.f,0.f,0.f,0.f}; acc[mt][nt] = z; }
        for (int kt = 0; kt < 9; ++kt) {
            bf16x8 a0, a1, a2, a3;
            if (kt < 8) { a0 = ldsA_hs(0, kt); a1 = ldsA_hs(1, kt); a2 = ldsA_hs(2, kt); a3 = ldsA_hs(3, kt); }
            else        { a0 = ldsA_ds(0);     a1 = ldsA_ds(1);     a2 = ldsA_ds(2);     a3 = ldsA_ds(3); }
#pragma unroll
            for (int nt = 0; nt < 2; ++nt) {
                bf16x8 b = ldB(Wt + OFF_WD, 288, (wave << 5) + (nt << 4) + lr, kt);
                acc[0][nt] = MFMA16(a0, b, acc[0][nt]);
                acc[1][nt] = MFMA16(a1, b, acc[1][nt]);
                acc[2][nt] = MFMA16(a2, b, acc[2][nt]);
                acc[3][nt] = MFMA16(a3, b, acc[3][nt]);
            }
        }
        __syncthreads();
#pragma unroll
        for (int nt = 0; nt < 2; ++nt) {
            int col = (wave << 5) + (nt << 4) + lr;
            float bv = P.bdv[col];
#pragma unroll
            for (int mt = 0; mt < 4; ++mt) {
#pragma unroll
                for (int e = 0; e < 4; ++e) {
                    int row = (mt << 4) + crow + e;
                    float z = fmaxf(acc[mt][nt][e] + bv, 0.f);
                    *(unsigned short*)(HsB + ((row * 512 + col * 2) ^ ((row & 7) << 4))) = f2bf(z);
                }
            }
        }
        __syncthreads();
    }

    // rgb = sigmoid(d @ wr + br)  (VALU, 4 threads/row over K=128)
    {
        int rr = t >> 2, q = t & 3;
        float c0 = 0.f, c1 = 0.f, c2 = 0.f;
#pragma unroll
        for (int j = 0; j < 4; ++j) {
            int kb = q * 32 + j * 8;
            bf16x8 d8 = *(const bf16x8*)(HsB + ((rr * 512 + kb * 2) ^ ((rr & 7) << 4)));
#pragma unroll
            for (int e = 0; e < 8; ++e) {
                float dv = (float)d8[e];
                const float* w = P.wrv + (kb + e) * 3;
                c0 += dv * w[0]; c1 += dv * w[1]; c2 += dv * w[2];
            }
        }
        c0 += __shfl_xor(c0, 1); c0 += __shfl_xor(c0, 2);
        c1 += __shfl_xor(c1, 1); c1 += __shfl_xor(c1, 2);
        c2 += __shfl_xor(c2, 1); c2 += __shfl_xor(c2, 2);
        if (q == 0) {
            size_t o = (size_t)(blockRow + rr) * 4;
            P.out[o + 0] = 1.f / (1.f + __expf(-(c0 + P.brv[0])));
            P.out[o + 1] = 1.f / (1.f + __expf(-(c1 + P.brv[1])));
            P.out[o + 2] = 1.f / (1.f + __expf(-(c2 + P.brv[2])));
        }
    }
}

extern "C" void kernel_launch(void* const* d_in, const int* in_sizes, int n_in,
                              void* d_out, int out_size, void* d_ws, size_t ws_size,
                              hipStream_t stream) {
    const float* x = (const float*)d_in[0];
    const float* w[8];
    const float* b[8];
    for (int i = 0; i < 8; ++i) {
        w[i] = (const float*)d_in[1 + 2 * i];
        b[i] = (const float*)d_in[2 + 2 * i];
    }
    const float* wf  = (const float*)d_in[17];
    const float* bfv = (const float*)d_in[18];
    const float* wd  = (const float*)d_in[19];
    const float* bdv = (const float*)d_in[20];
    const float* wsv = (const float*)d_in[21];
    const float* bsv = (const float*)d_in[22];
    const float* wrv = (const float*)d_in[23];
    const float* brv = (const float*)d_in[24];

    unsigned short* Wt = (unsigned short*)d_ws;  // needs W_TOTAL*2 = 1.19 MB

    prep_kernel<<<(W_TOTAL + 255) / 256, 256, 0, stream>>>(
        w[0], w[1], w[2], w[3], w[4], w[5], w[6], w[7], wf, wd, Wt);

    Params P;
    P.x = x; P.Wt = Wt;
    for (int i = 0; i < 8; ++i) P.b[i] = b[i];
    P.bfv = bfv; P.bdv = bdv; P.wsv = wsv; P.bsv = bsv; P.wrv = wrv; P.brv = brv;
    P.out = (float*)d_out;

    nerf_kernel<<<262144 / 64, 256, 0, stream>>>(P);
}